// Round 3
// baseline (489.679 us; speedup 1.0000x reference)
//
#include <hip/hip_runtime.h>
#include <hip/hip_bf16.h>
#include <math.h>

// CrossMamba MI355X — round 2: split-bf16 MFMA for big GEMMs, dt-precompute
// GEMM, LDS-free scan with uniform B/C loads, merged direction launches.

#define L_TOT 4096
#define LCTX  2048
#define DMODEL 512
#define DI 1024
#define DR 32
#define DS 16
#define NB 2
#define CS 64
#define NC 64   // L_TOT / CS

typedef __attribute__((ext_vector_type(8))) short short8v;
typedef __attribute__((ext_vector_type(4))) short short4v;
typedef __attribute__((ext_vector_type(4))) float f32x4;

__device__ __forceinline__ float siluf(float v) {
    return v / (1.f + __expf(-v));
}
__device__ __forceinline__ float softplusf_(float x) {
    return fmaxf(x, 0.f) + log1pf(__expf(-fabsf(x)));   // matches jax.nn.softplus
}
// RNE round f32 -> bf16 (bit-exact, no API dependence). Returns bf16 bits,
// sets hf to the rounded value as f32.
__device__ __forceinline__ short bfhi(float v, float& hf) {
    unsigned u = __float_as_uint(v);
    unsigned t = u + 0x7FFFu + ((u >> 16) & 1u);
    hf = __uint_as_float(t & 0xFFFF0000u);
    return (short)(t >> 16);
}

// ---------------------------------------------------------------------------
// Split x = (context|query)+seg into bf16 hi/lo arrays [8192][512].
// ---------------------------------------------------------------------------
__global__ __launch_bounds__(256) void k_split_x(
    const float* __restrict__ query, const float* __restrict__ context,
    const float* __restrict__ segc, const float* __restrict__ segq,
    short* __restrict__ xh, short* __restrict__ xl)
{
    const int t = blockIdx.x * 256 + threadIdx.x;   // over 8192*512/4
    const int e4 = t << 2;
    const int m = e4 >> 9, k4 = e4 & 511;
    const int b = m >> 12, l = m & (L_TOT - 1);
    const float* src; const float* seg;
    if (l < LCTX) { src = context + ((size_t)b * LCTX + l) * DMODEL;          seg = segc; }
    else          { src = query   + ((size_t)b * LCTX + (l - LCTX)) * DMODEL; seg = segq; }
    float4 v = *(const float4*)(src + k4);
    float4 s = *(const float4*)(seg + k4);
    float vv[4] = {v.x + s.x, v.y + s.y, v.z + s.z, v.w + s.w};
    short4v hi, lo;
    #pragma unroll
    for (int i = 0; i < 4; i++) {
        float hf, lf;
        hi[i] = bfhi(vv[i], hf);
        lo[i] = bfhi(vv[i] - hf, lf);
    }
    *(short4v*)(xh + (size_t)m * DMODEL + k4) = hi;
    *(short4v*)(xl + (size_t)m * DMODEL + k4) = lo;
}

// Generic f32 -> bf16 hi/lo split (for weights).
__global__ __launch_bounds__(256) void k_split_w(
    const float* __restrict__ w, short* __restrict__ wh, short* __restrict__ wl, int n4)
{
    const int t = blockIdx.x * 256 + threadIdx.x;
    if (t >= n4) return;
    float4 v = *(const float4*)(w + (size_t)t * 4);
    float vv[4] = {v.x, v.y, v.z, v.w};
    short4v hi, lo;
    #pragma unroll
    for (int i = 0; i < 4; i++) {
        float hf, lf;
        hi[i] = bfhi(vv[i], hf);
        lo[i] = bfhi(vv[i] - hf, lf);
    }
    *(short4v*)(wh + (size_t)t * 4) = hi;
    *(short4v*)(wl + (size_t)t * 4) = lo;
}

// ---------------------------------------------------------------------------
// Split-bf16 MFMA GEMM, tile 64x64, BK=32, 4 waves (wave = 16-row slice).
// C[m][n] = sum_k A[m][k]*B[n][k], A=[M][K] hi/lo, B=[N][K] hi/lo.
// Fragment maps (verified, learn_hip m89): a[j]=A[lane&15][(lane>>4)*8+j],
// b[j]=B'[(lane>>4)*8+j][lane&15] (B'=W^T), d[r]: row=(lane>>4)*4+r, col=lane&15.
// ---------------------------------------------------------------------------
__global__ __launch_bounds__(256) void k_gemm_xz_mfma(
    const short* __restrict__ xh, const short* __restrict__ xl,
    const short* __restrict__ wh, const short* __restrict__ wl,
    float* __restrict__ xi, float* __restrict__ z2)
{
    const int m0 = blockIdx.x * 64;
    const int n0 = blockIdx.y * 64;
    const int l0 = m0 & (L_TOT - 1);
    if (n0 >= DI && l0 < LCTX) return;      // z only needed for l >= 2048

    __shared__ short Ah[64][40], Al[64][40], Bh[64][40], Bl[64][40];
    const int tid = threadIdx.x;
    const int wave = tid >> 6, lane = tid & 63;
    const int srow = tid >> 2;              // staging row 0..63
    const int sc8  = (tid & 3) << 3;        // staging k-chunk 0,8,16,24
    const int fr = lane & 15;
    const int fk = (lane >> 4) << 3;

    f32x4 acc[4] = {{0.f,0.f,0.f,0.f},{0.f,0.f,0.f,0.f},{0.f,0.f,0.f,0.f},{0.f,0.f,0.f,0.f}};

    const size_t arow = (size_t)(m0 + srow) * DMODEL + sc8;
    const size_t brow = (size_t)(n0 + srow) * DMODEL + sc8;
    for (int k0 = 0; k0 < DMODEL; k0 += 32) {
        *(short8v*)&Ah[srow][sc8] = *(const short8v*)(xh + arow + k0);
        *(short8v*)&Al[srow][sc8] = *(const short8v*)(xl + arow + k0);
        *(short8v*)&Bh[srow][sc8] = *(const short8v*)(wh + brow + k0);
        *(short8v*)&Bl[srow][sc8] = *(const short8v*)(wl + brow + k0);
        __syncthreads();
        short8v ah = *(short8v*)&Ah[wave * 16 + fr][fk];
        short8v al = *(short8v*)&Al[wave * 16 + fr][fk];
        #pragma unroll
        for (int nf = 0; nf < 4; nf++) {
            short8v bh = *(short8v*)&Bh[nf * 16 + fr][fk];
            short8v bl = *(short8v*)&Bl[nf * 16 + fr][fk];
            acc[nf] = __builtin_amdgcn_mfma_f32_16x16x32_bf16(ah, bh, acc[nf], 0, 0, 0);
            acc[nf] = __builtin_amdgcn_mfma_f32_16x16x32_bf16(ah, bl, acc[nf], 0, 0, 0);
            acc[nf] = __builtin_amdgcn_mfma_f32_16x16x32_bf16(al, bh, acc[nf], 0, 0, 0);
        }
        __syncthreads();
    }
    #pragma unroll
    for (int nf = 0; nf < 4; nf++) {
        const int nn = n0 + nf * 16 + fr;
        #pragma unroll
        for (int j = 0; j < 4; j++) {
            const int mm = m0 + wave * 16 + ((lane >> 4) << 2) + j;
            const int b = mm >> 12, ll = mm & (L_TOT - 1);
            const float v = acc[nf][j];
            if (nn < DI)
                xi[((size_t)b * L_TOT + ll) * DI + nn] = v;
            else if (ll >= LCTX)
                z2[((size_t)b * LCTX + (ll - LCTX)) * DI + (nn - DI)] = v;
        }
    }
}

// Same structure for the output GEMM: A=yc [4096][1024], B=Wout [512][1024].
__global__ __launch_bounds__(256) void k_gemm_out_mfma(
    const short* __restrict__ ah_, const short* __restrict__ al_,
    const short* __restrict__ wh, const short* __restrict__ wl,
    float* __restrict__ out)
{
    const int m0 = blockIdx.x * 64;
    const int n0 = blockIdx.y * 64;

    __shared__ short Ah[64][40], Al[64][40], Bh[64][40], Bl[64][40];
    const int tid = threadIdx.x;
    const int wave = tid >> 6, lane = tid & 63;
    const int srow = tid >> 2;
    const int sc8  = (tid & 3) << 3;
    const int fr = lane & 15;
    const int fk = (lane >> 4) << 3;

    f32x4 acc[4] = {{0.f,0.f,0.f,0.f},{0.f,0.f,0.f,0.f},{0.f,0.f,0.f,0.f},{0.f,0.f,0.f,0.f}};

    const size_t arow = (size_t)(m0 + srow) * DI + sc8;
    const size_t brow = (size_t)(n0 + srow) * DI + sc8;
    for (int k0 = 0; k0 < DI; k0 += 32) {
        *(short8v*)&Ah[srow][sc8] = *(const short8v*)(ah_ + arow + k0);
        *(short8v*)&Al[srow][sc8] = *(const short8v*)(al_ + arow + k0);
        *(short8v*)&Bh[srow][sc8] = *(const short8v*)(wh + brow + k0);
        *(short8v*)&Bl[srow][sc8] = *(const short8v*)(wl + brow + k0);
        __syncthreads();
        short8v ah = *(short8v*)&Ah[wave * 16 + fr][fk];
        short8v al = *(short8v*)&Al[wave * 16 + fr][fk];
        #pragma unroll
        for (int nf = 0; nf < 4; nf++) {
            short8v bh = *(short8v*)&Bh[nf * 16 + fr][fk];
            short8v bl = *(short8v*)&Bl[nf * 16 + fr][fk];
            acc[nf] = __builtin_amdgcn_mfma_f32_16x16x32_bf16(ah, bh, acc[nf], 0, 0, 0);
            acc[nf] = __builtin_amdgcn_mfma_f32_16x16x32_bf16(ah, bl, acc[nf], 0, 0, 0);
            acc[nf] = __builtin_amdgcn_mfma_f32_16x16x32_bf16(al, bh, acc[nf], 0, 0, 0);
        }
        __syncthreads();
    }
    #pragma unroll
    for (int nf = 0; nf < 4; nf++) {
        const int nn = n0 + nf * 16 + fr;
        #pragma unroll
        for (int j = 0; j < 4; j++) {
            const int mm = m0 + wave * 16 + ((lane >> 4) << 2) + j;
            out[(size_t)mm * 512 + nn] = acc[nf][j];
        }
    }
}

// ---------------------------------------------------------------------------
// Depthwise conv-4 + bias + SiLU, both directions.
// ---------------------------------------------------------------------------
__global__ __launch_bounds__(256) void k_conv(
    const float* __restrict__ xi, const float* __restrict__ cw,
    const float* __restrict__ cb, float* __restrict__ xcf, float* __restrict__ xcb)
{
    const int t = blockIdx.x * 256 + threadIdx.x;
    const int d4 = (t & (DI / 4 - 1)) << 2;
    const int bl = t >> 8;
    const int l = bl & (L_TOT - 1);
    const int b = bl >> 12;

    float4 w0 = *(const float4*)(cw + (d4 + 0) * 4);
    float4 w1 = *(const float4*)(cw + (d4 + 1) * 4);
    float4 w2 = *(const float4*)(cw + (d4 + 2) * 4);
    float4 w3 = *(const float4*)(cw + (d4 + 3) * 4);
    float4 bias = *(const float4*)(cb + d4);

    float4 r[7];
    #pragma unroll
    for (int tt = -3; tt <= 3; tt++) {
        int ll = l + tt;
        if (ll >= 0 && ll < L_TOT)
            r[tt + 3] = *(const float4*)(xi + ((size_t)b * L_TOT + ll) * DI + d4);
        else
            r[tt + 3] = make_float4(0.f, 0.f, 0.f, 0.f);
    }
    float4 f, g;
    f.x = w0.x*r[0].x + w0.y*r[1].x + w0.z*r[2].x + w0.w*r[3].x + bias.x;
    f.y = w1.x*r[0].y + w1.y*r[1].y + w1.z*r[2].y + w1.w*r[3].y + bias.y;
    f.z = w2.x*r[0].z + w2.y*r[1].z + w2.z*r[2].z + w2.w*r[3].z + bias.z;
    f.w = w3.x*r[0].w + w3.y*r[1].w + w3.z*r[2].w + w3.w*r[3].w + bias.w;
    g.x = w0.x*r[6].x + w0.y*r[5].x + w0.z*r[4].x + w0.w*r[3].x + bias.x;
    g.y = w1.x*r[6].y + w1.y*r[5].y + w1.z*r[4].y + w1.w*r[3].y + bias.y;
    g.z = w2.x*r[6].z + w2.y*r[5].z + w2.z*r[4].z + w2.w*r[3].z + bias.z;
    g.w = w3.x*r[6].w + w3.y*r[5].w + w3.z*r[4].w + w3.w*r[3].w + bias.w;
    f.x = siluf(f.x); f.y = siluf(f.y); f.z = siluf(f.z); f.w = siluf(f.w);
    g.x = siluf(g.x); g.y = siluf(g.y); g.z = siluf(g.z); g.w = siluf(g.w);
    size_t o = (size_t)bl * DI + d4;
    *(float4*)(xcf + o) = f;
    *(float4*)(xcb + o) = g;
}

// ---------------------------------------------------------------------------
// dbl = xc @ Wx^T (f32 VALU, N=64, K=1024), fwd+bwd merged via blockIdx.z.
// ---------------------------------------------------------------------------
__global__ __launch_bounds__(256) void k_gemm_dbl(
    const float* __restrict__ xcf, const float* __restrict__ xcb,
    const float* __restrict__ Wx, float* __restrict__ dblf, float* __restrict__ dblb)
{
    const int dir = blockIdx.z;
    const int m0 = blockIdx.x * 64;
    if (dir && (m0 & (L_TOT - 1)) < LCTX) return;
    const float* A = dir ? xcb : xcf;
    float* C = dir ? dblb : dblf;

    __shared__ float As[16][68];
    __shared__ float Bs[16][68];
    const int tid = threadIdx.x;
    const int tx = tid & 15, ty = tid >> 4;
    const int lrow = tid >> 2;
    const int lk4  = (tid & 3) << 2;

    const float* arow = A  + (size_t)(m0 + lrow) * DI;
    const float* brow = Wx + (size_t)lrow * DI;

    float acc[4][4] = {};
    for (int k0 = 0; k0 < DI; k0 += 16) {
        float4 av = *(const float4*)(arow + k0 + lk4);
        As[lk4 + 0][lrow] = av.x;
        As[lk4 + 1][lrow] = av.y;
        As[lk4 + 2][lrow] = av.z;
        As[lk4 + 3][lrow] = av.w;
        float4 bv = *(const float4*)(brow + k0 + lk4);
        Bs[lk4 + 0][lrow] = bv.x;
        Bs[lk4 + 1][lrow] = bv.y;
        Bs[lk4 + 2][lrow] = bv.z;
        Bs[lk4 + 3][lrow] = bv.w;
        __syncthreads();
        #pragma unroll
        for (int kk = 0; kk < 16; kk++) {
            float4 a = *(const float4*)&As[kk][ty << 2];
            float4 w = *(const float4*)&Bs[kk][tx << 2];
            float a_[4] = {a.x, a.y, a.z, a.w};
            float w_[4] = {w.x, w.y, w.z, w.w};
            #pragma unroll
            for (int i = 0; i < 4; i++)
                #pragma unroll
                for (int j = 0; j < 4; j++)
                    acc[i][j] += a_[i] * w_[j];
        }
        __syncthreads();
    }
    #pragma unroll
    for (int i = 0; i < 4; i++) {
        int mm = m0 + (ty << 2) + i;
        int nn = tx << 2;
        *(float4*)(C + (size_t)mm * 64 + nn) =
            make_float4(acc[i][0], acc[i][1], acc[i][2], acc[i][3]);
    }
}

// ---------------------------------------------------------------------------
// dt = softplus(dbl[:, :32] @ Wdt^T + bdt). fwd full, bwd upper half (compact).
// grid (1024, 4, 4): z = dir*2+b; thread owns 1 d, 4 consecutive m.
// ---------------------------------------------------------------------------
__global__ __launch_bounds__(256) void k_gemm_dt(
    const float* __restrict__ dblf, const float* __restrict__ dblb,
    const float* __restrict__ Wdt, const float* __restrict__ bdt,
    float* __restrict__ dtf, float* __restrict__ dtb)
{
    const int z = blockIdx.z;
    const int dir = z >> 1, b = z & 1;
    const int mbase = blockIdx.x * 4;
    if (dir && mbase >= LCTX) return;
    const int l0 = dir ? LCTX + mbase : mbase;
    const int d = blockIdx.y * 256 + threadIdx.x;
    const float* dbl = dir ? dblb : dblf;

    float wd[DR];
    #pragma unroll
    for (int r = 0; r < DR; r += 4) {
        float4 v = *(const float4*)(Wdt + (size_t)d * DR + r);
        wd[r] = v.x; wd[r+1] = v.y; wd[r+2] = v.z; wd[r+3] = v.w;
    }
    const float bd = bdt[d];
    #pragma unroll
    for (int i = 0; i < 4; i++) {
        const int l = l0 + i;
        const float* row = dbl + ((size_t)b * L_TOT + l) * 64;
        float acc = bd;
        #pragma unroll
        for (int r = 0; r < DR; r += 4) {
            float4 v = *(const float4*)(row + r);
            acc += v.x * wd[r] + v.y * wd[r+1] + v.z * wd[r+2] + v.w * wd[r+3];
        }
        const float dt = softplusf_(acc);
        if (!dir) dtf[((size_t)b * L_TOT + l) * DI + d] = dt;
        else      dtb[((size_t)b * LCTX + (l - LCTX)) * DI + d] = dt;
    }
}

// ---------------------------------------------------------------------------
// Scan phase 1: per (dir,b,chunk,d): P = prod(dA), O = h(end | h0=0).
// No LDS: B row reads are wave-uniform float4s; dt precomputed.
// ---------------------------------------------------------------------------
__global__ __launch_bounds__(256) void k_scan_p1(
    const float* __restrict__ xcf, const float* __restrict__ xcb,
    const float* __restrict__ dblf, const float* __restrict__ dblb,
    const float* __restrict__ dtf, const float* __restrict__ dtb,
    const float* __restrict__ Alog,
    float* __restrict__ Pg, float* __restrict__ Og)
{
    const int c  = blockIdx.x;
    const int g  = blockIdx.y;
    const int db = blockIdx.z;
    const int dir = db >> 1, b = db & 1;
    if (dir == 1 && c < NC / 2) return;
    const int d = g * 256 + threadIdx.x;
    const float* xc  = dir ? xcb  : xcf;
    const float* dbl = dir ? dblb : dblf;

    float A2[DS];
    #pragma unroll
    for (int s = 0; s < DS; s++) A2[s] = -__expf(Alog[(size_t)d * DS + s]);

    float h[DS], P[DS];
    #pragma unroll
    for (int s = 0; s < DS; s++) { h[s] = 0.f; P[s] = 1.f; }

    for (int i = 0; i < CS; i++) {
        const int li = dir ? (CS - 1 - i) : i;
        const int l  = c * CS + li;
        const float dt = dir ? dtb[((size_t)b * LCTX + (l - LCTX)) * DI + d]
                             : dtf[((size_t)b * L_TOT + l) * DI + d];
        const float x = xc[((size_t)b * L_TOT + l) * DI + d];
        const float dtx = dt * x;
        const float* br = dbl + ((size_t)b * L_TOT + l) * 64 + DR;
        float4 B0 = *(const float4*)(br + 0);
        float4 B1 = *(const float4*)(br + 4);
        float4 B2 = *(const float4*)(br + 8);
        float4 B3 = *(const float4*)(br + 12);
        float Bv[DS] = {B0.x,B0.y,B0.z,B0.w, B1.x,B1.y,B1.z,B1.w,
                        B2.x,B2.y,B2.z,B2.w, B3.x,B3.y,B3.z,B3.w};
        #pragma unroll
        for (int s = 0; s < DS; s++) {
            float dA = __expf(dt * A2[s]);
            h[s] = dA * h[s] + dtx * Bv[s];
            P[s] *= dA;
        }
    }
    size_t base = (((size_t)db * NC + c) * DS) * DI + d;
    #pragma unroll
    for (int s = 0; s < DS; s++) {
        Pg[base + (size_t)s * DI] = P[s];
        Og[base + (size_t)s * DI] = h[s];
    }
}

// ---------------------------------------------------------------------------
// Scan phase 2: chunk-level scan; store h at entry of chunks 32..63.
// ---------------------------------------------------------------------------
__global__ __launch_bounds__(256) void k_scan_p2(
    const float* __restrict__ Pg, const float* __restrict__ Og,
    float* __restrict__ hs)
{
    const int d  = blockIdx.x * 256 + threadIdx.x;
    const int s  = blockIdx.y;
    const int db = blockIdx.z;
    const int dir = db >> 1;
    float h = 0.f;
    if (dir == 0) {
        for (int c = 0; c < NC; c++) {
            if (c >= NC / 2)
                hs[(((size_t)db * (NC/2) + (c - NC/2)) * DS + s) * DI + d] = h;
            size_t idx = (((size_t)db * NC + c) * DS + s) * DI + d;
            h = Pg[idx] * h + Og[idx];
        }
    } else {
        for (int c = NC - 1; c >= NC / 2; c--) {
            hs[(((size_t)db * (NC/2) + (c - NC/2)) * DS + s) * DI + d] = h;
            size_t idx = (((size_t)db * NC + c) * DS + s) * DI + d;
            h = Pg[idx] * h + Og[idx];
        }
    }
}

// ---------------------------------------------------------------------------
// Scan phase 3: re-scan chunks 32..63 with correct h0, emit y per direction
// into separate buffers (fwd->ysf, bwd->ysb2). grid (32,4,4).
// ---------------------------------------------------------------------------
__global__ __launch_bounds__(256) void k_scan_p3(
    const float* __restrict__ xcf, const float* __restrict__ xcb,
    const float* __restrict__ dblf, const float* __restrict__ dblb,
    const float* __restrict__ dtf, const float* __restrict__ dtb,
    const float* __restrict__ Alog, const float* __restrict__ hs,
    float* __restrict__ ysf, float* __restrict__ ysb2)
{
    const int c = blockIdx.x + NC / 2;
    const int g = blockIdx.y;
    const int db = blockIdx.z;
    const int dir = db >> 1, b = db & 1;
    const int d = g * 256 + threadIdx.x;
    const float* xc  = dir ? xcb  : xcf;
    const float* dbl = dir ? dblb : dblf;
    float* ys = dir ? ysb2 : ysf;

    float A2[DS];
    #pragma unroll
    for (int s = 0; s < DS; s++) A2[s] = -__expf(Alog[(size_t)d * DS + s]);

    float h[DS];
    #pragma unroll
    for (int s = 0; s < DS; s++)
        h[s] = hs[(((size_t)db * (NC/2) + (c - NC/2)) * DS + s) * DI + d];

    for (int i = 0; i < CS; i++) {
        const int li = dir ? (CS - 1 - i) : i;
        const int l  = c * CS + li;
        const float dt = dir ? dtb[((size_t)b * LCTX + (l - LCTX)) * DI + d]
                             : dtf[((size_t)b * L_TOT + l) * DI + d];
        const float x = xc[((size_t)b * L_TOT + l) * DI + d];
        const float dtx = dt * x;
        const float* br = dbl + ((size_t)b * L_TOT + l) * 64 + DR;
        float4 B0 = *(const float4*)(br + 0);
        float4 B1 = *(const float4*)(br + 4);
        float4 B2 = *(const float4*)(br + 8);
        float4 B3 = *(const float4*)(br + 12);
        float4 C0 = *(const float4*)(br + 16);
        float4 C1 = *(const float4*)(br + 20);
        float4 C2 = *(const float4*)(br + 24);
        float4 C3 = *(const float4*)(br + 28);
        float Bv[DS] = {B0.x,B0.y,B0.z,B0.w, B1.x,B1.y,B1.z,B1.w,
                        B2.x,B2.y,B2.z,B2.w, B3.x,B3.y,B3.z,B3.w};
        float Cv[DS] = {C0.x,C0.y,C0.z,C0.w, C1.x,C1.y,C1.z,C1.w,
                        C2.x,C2.y,C2.z,C2.w, C3.x,C3.y,C3.z,C3.w};
        float y = 0.f;
        #pragma unroll
        for (int s = 0; s < DS; s++) {
            float dA = __expf(dt * A2[s]);
            h[s] = dA * h[s] + dtx * Bv[s];
            y += h[s] * Cv[s];
        }
        ys[((size_t)b * LCTX + (l - LCTX)) * DI + d] = y;
    }
}

// ---------------------------------------------------------------------------
// y-combine -> split bf16 hi/lo for the out-GEMM A operand.
// yc = 0.5 * silu(z) * (ysf + ysb + (xcf + xcb) * D)
// ---------------------------------------------------------------------------
__global__ __launch_bounds__(256) void k_ycomb(
    const float* __restrict__ ysf, const float* __restrict__ ysb2,
    const float* __restrict__ xcf, const float* __restrict__ xcb,
    const float* __restrict__ z2, const float* __restrict__ Dg,
    short* __restrict__ ych, short* __restrict__ ycl)
{
    const int t = blockIdx.x * 256 + threadIdx.x;   // over NB*LCTX*DI/4
    const int d4 = (t & 255) << 2;
    const int bo = t >> 8;
    const int o = bo & (LCTX - 1);
    const int b = bo >> 11;
    const size_t il = ((size_t)b * L_TOT + (o + LCTX)) * DI + d4;
    const size_t io = ((size_t)b * LCTX + o) * DI + d4;
    float4 yf  = *(const float4*)(ysf + io);
    float4 yb  = *(const float4*)(ysb2 + io);
    float4 cf  = *(const float4*)(xcf + il);
    float4 cbk = *(const float4*)(xcb + il);
    float4 zv  = *(const float4*)(z2 + io);
    float4 dv  = *(const float4*)(Dg + d4);
    float rr[4];
    rr[0] = 0.5f * siluf(zv.x) * (yf.x + yb.x + (cf.x + cbk.x) * dv.x);
    rr[1] = 0.5f * siluf(zv.y) * (yf.y + yb.y + (cf.y + cbk.y) * dv.y);
    rr[2] = 0.5f * siluf(zv.z) * (yf.z + yb.z + (cf.z + cbk.z) * dv.z);
    rr[3] = 0.5f * siluf(zv.w) * (yf.w + yb.w + (cf.w + cbk.w) * dv.w);
    short4v hi, lo;
    #pragma unroll
    for (int i = 0; i < 4; i++) {
        float hf, lf;
        hi[i] = bfhi(rr[i], hf);
        lo[i] = bfhi(rr[i] - hf, lf);
    }
    *(short4v*)(ych + io) = hi;
    *(short4v*)(ycl + io) = lo;
}

// ---------------------------------------------------------------------------
extern "C" void kernel_launch(void* const* d_in, const int* in_sizes, int n_in,
                              void* d_out, int out_size, void* d_ws, size_t ws_size,
                              hipStream_t stream)
{
    const float* query   = (const float*)d_in[0];
    const float* context = (const float*)d_in[1];
    const float* segc    = (const float*)d_in[2];
    const float* segq    = (const float*)d_in[3];
    const float* Win     = (const float*)d_in[4];
    const float* cw      = (const float*)d_in[5];
    const float* cb      = (const float*)d_in[6];
    const float* Wx      = (const float*)d_in[7];
    const float* Wdt     = (const float*)d_in[8];
    const float* bdt     = (const float*)d_in[9];
    const float* Alog    = (const float*)d_in[10];
    const float* Dg      = (const float*)d_in[11];
    const float* Wout    = (const float*)d_in[12];
    float* out = (float*)d_out;

    float* ws   = (float*)d_ws;
    float* xi   = ws;                      // [2][4096][1024] f32 (reused as dtf)
    float* z2   = xi   + 8388608;          // [2][2048][1024]
    float* xcf  = z2   + 4194304;          // [2][4096][1024]
    float* xcb  = xcf  + 8388608;          // [2][4096][1024]
    float* dblf = xcb  + 8388608;          // [2][4096][64]
    float* dblb = dblf + 524288;           // [2][4096][64]
    float* dtb  = dblb + 524288;           // [2][2048][1024]
    float* Pg   = dtb  + 4194304;          // [4][64][16][1024]
    float* Og   = Pg   + 4194304;          // [4][64][16][1024]
    float* hsb  = Og   + 4194304;          // [4][32][16][1024]
    float* ysf  = hsb  + 2097152;          // [2][2048][1024]
    float* ysb2 = ysf  + 4194304;          // [2][2048][1024]
    short* xh    = (short*)(ysb2 + 4194304);  // [8192][512] bf16 (reused as ych)
    short* xl    = xh    + 4194304;           // (reused as ycl)
    short* winh  = xl    + 4194304;           // [2048][512]
    short* winl  = winh  + 1048576;
    short* wouth = winl  + 1048576;           // [512][1024]
    short* woutl = wouth + 524288;
    float* dtf = xi;   // alias: xi dead after k_conv
    short* ych = xh;   // alias: xh/xl dead after k_gemm_xz_mfma
    short* ycl = xl;
    // total ~237 MB

    // 1) splits
    k_split_x<<<dim3(4096), 256, 0, stream>>>(query, context, segc, segq, xh, xl);
    k_split_w<<<dim3(1024), 256, 0, stream>>>(Win, winh, winl, 2048 * 512 / 4);
    k_split_w<<<dim3(512), 256, 0, stream>>>(Wout, wouth, woutl, 512 * 1024 / 4);
    // 2) xz GEMM (split-bf16 MFMA)
    k_gemm_xz_mfma<<<dim3(128, 32), 256, 0, stream>>>(xh, xl, winh, winl, xi, z2);
    // 3) conv
    k_conv<<<dim3(8192), 256, 0, stream>>>(xi, cw, cb, xcf, xcb);
    // 4) dbl GEMM (f32, both dirs)
    k_gemm_dbl<<<dim3(128, 1, 2), 256, 0, stream>>>(xcf, xcb, Wx, dblf, dblb);
    // 5) dt precompute (softplus fused)
    k_gemm_dt<<<dim3(1024, 4, 4), 256, 0, stream>>>(dblf, dblb, Wdt, bdt, dtf, dtb);
    // 6) chunked selective scan
    k_scan_p1<<<dim3(NC, 4, 4), 256, 0, stream>>>(xcf, xcb, dblf, dblb, dtf, dtb, Alog, Pg, Og);
    k_scan_p2<<<dim3(4, 16, 4), 256, 0, stream>>>(Pg, Og, hsb);
    k_scan_p3<<<dim3(NC/2, 4, 4), 256, 0, stream>>>(xcf, xcb, dblf, dblb, dtf, dtb, Alog, hsb, ysf, ysb2);
    // 7) combine + gate + bf16 split
    k_ycomb<<<dim3(4096), 256, 0, stream>>>(ysf, ysb2, xcf, xcb, z2, Dg, ych, ycl);
    // 8) out GEMM (split-bf16 MFMA)
    k_gemm_out_mfma<<<dim3(64, 8), 256, 0, stream>>>(ych, ycl, wouth, woutl, out);
}

// Round 6
// 368.973 us; speedup vs baseline: 1.3271x; 1.3271x over previous
//
#include <hip/hip_runtime.h>
#include <hip/hip_bf16.h>
#include <math.h>

// CrossMamba MI355X — round 5: round-4 structure, but gemm_core staging
// changed from global_load_lds+inline-asm (suspected replay-dependent race)
// to register-staged ds_write with the same XOR chunk swizzle. No inline asm.

#define L_TOT 4096
#define LCTX  2048
#define DMODEL 512
#define DI 1024
#define DR 32
#define DS 16
#define CS 64
#define NC 64

typedef _Float16 f16;
typedef __attribute__((ext_vector_type(8))) _Float16 f16x8;
typedef __attribute__((ext_vector_type(4))) float f32x4;

__device__ __forceinline__ float siluf(float v) {
    return v / (1.f + __expf(-v));
}
__device__ __forceinline__ float softplusf_(float x) {
    return fmaxf(x, 0.f) + log1pf(__expf(-fabsf(x)));   // matches jax.nn.softplus
}

// ---------------------------------------------------------------------------
// Shared MFMA GEMM core, register-staged. C[m][n] = sum_k A[m][k]*B[n][k],
// A/B fp16 row-major, row stride K. Tile BM=IF*32 x BN=JF*32, 4 waves (2x2).
// BK=64 per stage. LDS row = 64 f16 = 128B = 8 chunks of 16B; stored at
// physical chunk = logical ^ (row&7); read back with the same XOR -> the 16
// lanes of a quarter-wave (rows r=fr mod 8 spread) hit 8 distinct 16B slots.
// Staging: thread (srow=tid>>3, schk=tid&7) loads f16x8 per 32-row pass,
// barrier, ds_write_b128 swizzled, barrier, MFMA phase. All waits compiler-
// inserted; no inline asm, no async DMA.
// Frag maps (HW-verified r2): a[j]=A[fr][q*8+j], d: row=q*4+jj, col=fr.
// ---------------------------------------------------------------------------
template<int IF, int JF, int K>
__device__ __forceinline__ void gemm_core(
    const f16* __restrict__ Ab, const f16* __restrict__ Bb,
    f16* LA, f16* LB, f32x4 (&acc)[IF][JF])
{
    constexpr int PA = IF;               // 32-row passes for A (BM/32)
    constexpr int PB = JF;               // 32-row passes for B (BN/32)
    const int tid = threadIdx.x;
    const int wid = tid >> 6, lane = tid & 63;
    const int wr = wid >> 1, wc = wid & 1;
    const int fr = lane & 15, q = lane >> 4;
    const int srow = tid >> 3;           // 0..31
    const int schk = tid & 7;            // 0..7
    const int swz  = (schk ^ (srow & 7)) << 3;   // swizzled LDS chunk offset

    for (int k0 = 0; k0 < K; k0 += 64) {
        f16x8 ra[PA], rb[PB];
        #pragma unroll
        for (int p = 0; p < PA; p++)
            ra[p] = *(const f16x8*)(Ab + (size_t)(p * 32 + srow) * K + k0 + schk * 8);
        #pragma unroll
        for (int p = 0; p < PB; p++)
            rb[p] = *(const f16x8*)(Bb + (size_t)(p * 32 + srow) * K + k0 + schk * 8);
        __syncthreads();                 // previous tile fully consumed
        #pragma unroll
        for (int p = 0; p < PA; p++)
            *(f16x8*)(LA + (p * 32 + srow) * 64 + swz) = ra[p];
        #pragma unroll
        for (int p = 0; p < PB; p++)
            *(f16x8*)(LB + (p * 32 + srow) * 64 + swz) = rb[p];
        __syncthreads();                 // tile visible to all waves
        #pragma unroll
        for (int s = 0; s < 2; s++) {
            const int ph = ((s * 4 + q) ^ (fr & 7)) << 3;
            f16x8 af[IF], bf[JF];
            #pragma unroll
            for (int i = 0; i < IF; i++)
                af[i] = *(const f16x8*)&LA[(wr * IF * 16 + i * 16 + fr) * 64 + ph];
            #pragma unroll
            for (int j = 0; j < JF; j++)
                bf[j] = *(const f16x8*)&LB[(wc * JF * 16 + j * 16 + fr) * 64 + ph];
            #pragma unroll
            for (int i = 0; i < IF; i++)
                #pragma unroll
                for (int j = 0; j < JF; j++)
                    acc[i][j] = __builtin_amdgcn_mfma_f32_16x16x32_f16(
                        af[i], bf[j], acc[i][j], 0, 0, 0);
        }
    }
}

// ---------------------------------------------------------------------------
// xz GEMM: [8192][512] x [2048][512]^T. xi (n<1024) fp16 all rows; z (n>=1024)
// fp16 compact upper rows only; z-tiles skipped for l<2048.
// ---------------------------------------------------------------------------
__global__ __launch_bounds__(256) void k_gx(
    const f16* __restrict__ xf, const f16* __restrict__ winf,
    f16* __restrict__ xif, f16* __restrict__ z2f)
{
    const int m0 = blockIdx.x * 128;
    const int n0 = blockIdx.y * 128;
    if (n0 >= DI && (m0 & (L_TOT - 1)) < LCTX) return;
    __shared__ f16 LA[128 * 64];
    __shared__ f16 LB[128 * 64];
    f32x4 acc[4][4];
    #pragma unroll
    for (int i = 0; i < 4; i++)
        #pragma unroll
        for (int j = 0; j < 4; j++) acc[i][j] = (f32x4){0.f, 0.f, 0.f, 0.f};
    gemm_core<4, 4, DMODEL>(xf + (size_t)m0 * DMODEL, winf + (size_t)n0 * DMODEL,
                            LA, LB, acc);
    const int lane = threadIdx.x & 63, wid = threadIdx.x >> 6;
    const int wr = wid >> 1, wc = wid & 1, fr = lane & 15, q = lane >> 4;
    #pragma unroll
    for (int i = 0; i < 4; i++)
        #pragma unroll
        for (int j = 0; j < 4; j++)
            #pragma unroll
            for (int jj = 0; jj < 4; jj++) {
                const int mm = m0 + wr * 64 + i * 16 + q * 4 + jj;
                const int nn = n0 + wc * 64 + j * 16 + fr;
                const int b = mm >> 12, ll = mm & (L_TOT - 1);
                const f16 v = (f16)acc[i][j][jj];
                if (nn < DI)
                    xif[((size_t)b * L_TOT + ll) * DI + nn] = v;
                else if (ll >= LCTX)
                    z2f[((size_t)b * LCTX + (ll - LCTX)) * DI + (nn - DI)] = v;
            }
}

// ---------------------------------------------------------------------------
// dbl GEMM: xc rows x Wx[64][1024]^T -> f32. fwd: 64 blocks of 128 rows;
// bwd: 32 blocks over upper halves.
// ---------------------------------------------------------------------------
__global__ __launch_bounds__(256) void k_gdbl(
    const f16* __restrict__ xcff, const f16* __restrict__ xcbf,
    const f16* __restrict__ wxf, float* __restrict__ dblf, float* __restrict__ dblb)
{
    const int bx = blockIdx.x;
    const f16* Ab; float* Cb;
    if (bx < 64) {
        Ab = xcff + (size_t)bx * 128 * DI;
        Cb = dblf + (size_t)bx * 128 * 64;
    } else {
        const int idx = bx - 64;
        const int b = idx >> 4;
        const int l0 = LCTX + (idx & 15) * 128;
        const size_t r = (size_t)b * L_TOT + l0;
        Ab = xcbf + r * DI;
        Cb = dblb + r * 64;
    }
    __shared__ f16 LA[128 * 64];
    __shared__ f16 LB[64 * 64];
    f32x4 acc[4][2];
    #pragma unroll
    for (int i = 0; i < 4; i++)
        #pragma unroll
        for (int j = 0; j < 2; j++) acc[i][j] = (f32x4){0.f, 0.f, 0.f, 0.f};
    gemm_core<4, 2, DI>(Ab, wxf, LA, LB, acc);
    const int lane = threadIdx.x & 63, wid = threadIdx.x >> 6;
    const int wr = wid >> 1, wc = wid & 1, fr = lane & 15, q = lane >> 4;
    #pragma unroll
    for (int i = 0; i < 4; i++)
        #pragma unroll
        for (int j = 0; j < 2; j++)
            #pragma unroll
            for (int jj = 0; jj < 4; jj++) {
                const int rr = wr * 64 + i * 16 + q * 4 + jj;
                const int nn = wc * 32 + j * 16 + fr;
                Cb[(size_t)rr * 64 + nn] = acc[i][j][jj];
            }
}

// ---------------------------------------------------------------------------
// out GEMM: yc[4096][1024] x Wout[512][1024]^T -> out f32 [4096][512].
// ---------------------------------------------------------------------------
__global__ __launch_bounds__(256) void k_gout(
    const f16* __restrict__ ycf, const f16* __restrict__ woutf,
    float* __restrict__ out)
{
    const int m0 = blockIdx.x * 128;
    const int n0 = blockIdx.y * 64;
    __shared__ f16 LA[128 * 64];
    __shared__ f16 LB[64 * 64];
    f32x4 acc[4][2];
    #pragma unroll
    for (int i = 0; i < 4; i++)
        #pragma unroll
        for (int j = 0; j < 2; j++) acc[i][j] = (f32x4){0.f, 0.f, 0.f, 0.f};
    gemm_core<4, 2, DI>(ycf + (size_t)m0 * DI, woutf + (size_t)n0 * DI, LA, LB, acc);
    const int lane = threadIdx.x & 63, wid = threadIdx.x >> 6;
    const int wr = wid >> 1, wc = wid & 1, fr = lane & 15, q = lane >> 4;
    #pragma unroll
    for (int i = 0; i < 4; i++)
        #pragma unroll
        for (int j = 0; j < 2; j++)
            #pragma unroll
            for (int jj = 0; jj < 4; jj++) {
                const int mm = m0 + wr * 64 + i * 16 + q * 4 + jj;
                const int nn = n0 + wc * 32 + j * 16 + fr;
                out[(size_t)mm * 512 + nn] = acc[i][j][jj];
            }
}

// ---------------------------------------------------------------------------
// Prep: x = (context|query)+seg -> fp16 [8192][512]
// ---------------------------------------------------------------------------
__global__ __launch_bounds__(256) void k_prep_x(
    const float* __restrict__ query, const float* __restrict__ context,
    const float* __restrict__ segc, const float* __restrict__ segq,
    f16* __restrict__ xf)
{
    const int t = blockIdx.x * 256 + threadIdx.x;    // 0..524287
    const int e8 = t << 3;
    const int m = e8 >> 9, k8 = e8 & 511;
    const int b = m >> 12, l = m & (L_TOT - 1);
    const float* src; const float* seg;
    if (l < LCTX) { src = context + ((size_t)b * LCTX + l) * DMODEL;          seg = segc; }
    else          { src = query   + ((size_t)b * LCTX + (l - LCTX)) * DMODEL; seg = segq; }
    float4 v0 = *(const float4*)(src + k8);
    float4 v1 = *(const float4*)(src + k8 + 4);
    float4 s0 = *(const float4*)(seg + k8);
    float4 s1 = *(const float4*)(seg + k8 + 4);
    f16x8 o;
    o[0] = (f16)(v0.x + s0.x); o[1] = (f16)(v0.y + s0.y);
    o[2] = (f16)(v0.z + s0.z); o[3] = (f16)(v0.w + s0.w);
    o[4] = (f16)(v1.x + s1.x); o[5] = (f16)(v1.y + s1.y);
    o[6] = (f16)(v1.z + s1.z); o[7] = (f16)(v1.w + s1.w);
    *(f16x8*)(xf + (size_t)m * DMODEL + k8) = o;
}

// Prep weights: Win, Wx, Wout -> fp16 (one launch).
__global__ __launch_bounds__(256) void k_prep_w(
    const float* __restrict__ Win, const float* __restrict__ Wx,
    const float* __restrict__ Wout,
    f16* __restrict__ winf, f16* __restrict__ wxf, f16* __restrict__ woutf)
{
    const int t = blockIdx.x * 256 + threadIdx.x;    // 0..204799 (8-elem units)
    const float* src; f16* dst; size_t off;
    if (t < 131072)      { src = Win;  dst = winf;  off = (size_t)t * 8; }
    else if (t < 139264) { src = Wx;   dst = wxf;   off = (size_t)(t - 131072) * 8; }
    else                 { src = Wout; dst = woutf; off = (size_t)(t - 139264) * 8; }
    float4 a = *(const float4*)(src + off);
    float4 c = *(const float4*)(src + off + 4);
    f16x8 o;
    o[0] = (f16)a.x; o[1] = (f16)a.y; o[2] = (f16)a.z; o[3] = (f16)a.w;
    o[4] = (f16)c.x; o[5] = (f16)c.y; o[6] = (f16)c.z; o[7] = (f16)c.w;
    *(f16x8*)(dst + off) = o;
}

// ---------------------------------------------------------------------------
// Depthwise conv-4 + bias + SiLU, both directions, fp16 in/out (f32 math).
// ---------------------------------------------------------------------------
__global__ __launch_bounds__(256) void k_conv(
    const f16* __restrict__ xif, const float* __restrict__ cw,
    const float* __restrict__ cb, f16* __restrict__ xcff, f16* __restrict__ xcbf)
{
    const int t = blockIdx.x * 256 + threadIdx.x;    // 0..1048575
    const int d8 = (t & 127) << 3;
    const int bl = t >> 7;
    const int l = bl & (L_TOT - 1), b = bl >> 12;

    float w[8][4], bias[8];
    #pragma unroll
    for (int c = 0; c < 8; c++) {
        float4 wv = *(const float4*)(cw + (size_t)(d8 + c) * 4);
        w[c][0] = wv.x; w[c][1] = wv.y; w[c][2] = wv.z; w[c][3] = wv.w;
        bias[c] = cb[d8 + c];
    }
    float xv[7][8];
    #pragma unroll
    for (int tt = -3; tt <= 3; tt++) {
        const int ll = l + tt;
        if (ll >= 0 && ll < L_TOT) {
            f16x8 r = *(const f16x8*)(xif + ((size_t)b * L_TOT + ll) * DI + d8);
            #pragma unroll
            for (int c = 0; c < 8; c++) xv[tt + 3][c] = (float)r[c];
        } else {
            #pragma unroll
            for (int c = 0; c < 8; c++) xv[tt + 3][c] = 0.f;
        }
    }
    f16x8 fo, go;
    #pragma unroll
    for (int c = 0; c < 8; c++) {
        float f = w[c][0]*xv[0][c] + w[c][1]*xv[1][c] + w[c][2]*xv[2][c] + w[c][3]*xv[3][c] + bias[c];
        float g = w[c][0]*xv[6][c] + w[c][1]*xv[5][c] + w[c][2]*xv[4][c] + w[c][3]*xv[3][c] + bias[c];
        fo[c] = (f16)siluf(f);
        go[c] = (f16)siluf(g);
    }
    const size_t o = (size_t)bl * DI + d8;
    *(f16x8*)(xcff + o) = fo;
    *(f16x8*)(xcbf + o) = go;
}

// ---------------------------------------------------------------------------
// dt = softplus(dbl[:, :32] @ Wdt^T + bdt) -> fp16. fwd full, bwd compact upper.
// ---------------------------------------------------------------------------
__global__ __launch_bounds__(256) void k_dt(
    const float* __restrict__ dblf, const float* __restrict__ dblb,
    const float* __restrict__ Wdt, const float* __restrict__ bdt,
    f16* __restrict__ dtf, f16* __restrict__ dtb)
{
    const int z = blockIdx.z;
    const int dir = z >> 1, b = z & 1;
    const int mbase = blockIdx.x * 4;
    if (dir && mbase >= LCTX) return;
    const int l0 = dir ? LCTX + mbase : mbase;
    const int d = blockIdx.y * 256 + threadIdx.x;
    const float* dbl = dir ? dblb : dblf;

    float wd[DR];
    #pragma unroll
    for (int r = 0; r < DR; r += 4) {
        float4 v = *(const float4*)(Wdt + (size_t)d * DR + r);
        wd[r] = v.x; wd[r+1] = v.y; wd[r+2] = v.z; wd[r+3] = v.w;
    }
    const float bd = bdt[d];
    #pragma unroll
    for (int i = 0; i < 4; i++) {
        const int l = l0 + i;
        const float* row = dbl + ((size_t)b * L_TOT + l) * 64;
        float acc = bd;
        #pragma unroll
        for (int r = 0; r < DR; r += 4) {
            float4 v = *(const float4*)(row + r);
            acc += v.x * wd[r] + v.y * wd[r+1] + v.z * wd[r+2] + v.w * wd[r+3];
        }
        const float dt = softplusf_(acc);
        if (!dir) dtf[((size_t)b * L_TOT + l) * DI + d] = (f16)dt;
        else      dtb[((size_t)b * LCTX + (l - LCTX)) * DI + d] = (f16)dt;
    }
}

// ---------------------------------------------------------------------------
// Scan phase 1: per (dir,b,chunk,d): P = prod(dA), O = h(end | h0=0).
// ---------------------------------------------------------------------------
__global__ __launch_bounds__(256) void k_scan_p1(
    const f16* __restrict__ xcff, const f16* __restrict__ xcbf,
    const float* __restrict__ dblf, const float* __restrict__ dblb,
    const f16* __restrict__ dtf, const f16* __restrict__ dtb,
    const float* __restrict__ Alog,
    float* __restrict__ Pg, float* __restrict__ Og)
{
    const int c  = blockIdx.x;
    const int g  = blockIdx.y;
    const int db = blockIdx.z;
    const int dir = db >> 1, b = db & 1;
    if (dir == 1 && c < NC / 2) return;
    const int d = g * 256 + threadIdx.x;
    const f16* xc = dir ? xcbf : xcff;
    const float* dbl = dir ? dblb : dblf;

    float A2[DS];
    #pragma unroll
    for (int s = 0; s < DS; s++) A2[s] = -__expf(Alog[(size_t)d * DS + s]);

    float h[DS], P[DS];
    #pragma unroll
    for (int s = 0; s < DS; s++) { h[s] = 0.f; P[s] = 1.f; }

    for (int i = 0; i < CS; i++) {
        const int li = dir ? (CS - 1 - i) : i;
        const int l  = c * CS + li;
        const float dt = dir ? (float)dtb[((size_t)b * LCTX + (l - LCTX)) * DI + d]
                             : (float)dtf[((size_t)b * L_TOT + l) * DI + d];
        const float x = (float)xc[((size_t)b * L_TOT + l) * DI + d];
        const float dtx = dt * x;
        const float* br = dbl + ((size_t)b * L_TOT + l) * 64 + DR;
        float4 B0 = *(const float4*)(br + 0);
        float4 B1 = *(const float4*)(br + 4);
        float4 B2 = *(const float4*)(br + 8);
        float4 B3 = *(const float4*)(br + 12);
        float Bv[DS] = {B0.x,B0.y,B0.z,B0.w, B1.x,B1.y,B1.z,B1.w,
                        B2.x,B2.y,B2.z,B2.w, B3.x,B3.y,B3.z,B3.w};
        #pragma unroll
        for (int s = 0; s < DS; s++) {
            float dA = __expf(dt * A2[s]);
            h[s] = dA * h[s] + dtx * Bv[s];
            P[s] *= dA;
        }
    }
    size_t base = (((size_t)db * NC + c) * DS) * DI + d;
    #pragma unroll
    for (int s = 0; s < DS; s++) {
        Pg[base + (size_t)s * DI] = P[s];
        Og[base + (size_t)s * DI] = h[s];
    }
}

// ---------------------------------------------------------------------------
// Scan phase 2: chunk-level scan; store h at entry of chunks 32..63.
// ---------------------------------------------------------------------------
__global__ __launch_bounds__(256) void k_scan_p2(
    const float* __restrict__ Pg, const float* __restrict__ Og,
    float* __restrict__ hs)
{
    const int d  = blockIdx.x * 256 + threadIdx.x;
    const int s  = blockIdx.y;
    const int db = blockIdx.z;
    const int dir = db >> 1;
    float h = 0.f;
    if (dir == 0) {
        for (int c = 0; c < NC; c++) {
            if (c >= NC / 2)
                hs[(((size_t)db * (NC/2) + (c - NC/2)) * DS + s) * DI + d] = h;
            size_t idx = (((size_t)db * NC + c) * DS + s) * DI + d;
            h = Pg[idx] * h + Og[idx];
        }
    } else {
        for (int c = NC - 1; c >= NC / 2; c--) {
            hs[(((size_t)db * (NC/2) + (c - NC/2)) * DS + s) * DI + d] = h;
            size_t idx = (((size_t)db * NC + c) * DS + s) * DI + d;
            h = Pg[idx] * h + Og[idx];
        }
    }
}

// ---------------------------------------------------------------------------
// Scan phase 3: re-scan chunks 32..63 with correct h0; y -> fp16 per dir.
// ---------------------------------------------------------------------------
__global__ __launch_bounds__(256) void k_scan_p3(
    const f16* __restrict__ xcff, const f16* __restrict__ xcbf,
    const float* __restrict__ dblf, const float* __restrict__ dblb,
    const f16* __restrict__ dtf, const f16* __restrict__ dtb,
    const float* __restrict__ Alog, const float* __restrict__ hs,
    f16* __restrict__ ysf, f16* __restrict__ ysb)
{
    const int c = blockIdx.x + NC / 2;
    const int g = blockIdx.y;
    const int db = blockIdx.z;
    const int dir = db >> 1, b = db & 1;
    const int d = g * 256 + threadIdx.x;
    const f16* xc = dir ? xcbf : xcff;
    const float* dbl = dir ? dblb : dblf;
    f16* ys = dir ? ysb : ysf;

    float A2[DS];
    #pragma unroll
    for (int s = 0; s < DS; s++) A2[s] = -__expf(Alog[(size_t)d * DS + s]);

    float h[DS];
    #pragma unroll
    for (int s = 0; s < DS; s++)
        h[s] = hs[(((size_t)db * (NC/2) + (c - NC/2)) * DS + s) * DI + d];

    for (int i = 0; i < CS; i++) {
        const int li = dir ? (CS - 1 - i) : i;
        const int l  = c * CS + li;
        const float dt = dir ? (float)dtb[((size_t)b * LCTX + (l - LCTX)) * DI + d]
                             : (float)dtf[((size_t)b * L_TOT + l) * DI + d];
        const float x = (float)xc[((size_t)b * L_TOT + l) * DI + d];
        const float dtx = dt * x;
        const float* br = dbl + ((size_t)b * L_TOT + l) * 64 + DR;
        float4 B0 = *(const float4*)(br + 0);
        float4 B1 = *(const float4*)(br + 4);
        float4 B2 = *(const float4*)(br + 8);
        float4 B3 = *(const float4*)(br + 12);
        float4 C0 = *(const float4*)(br + 16);
        float4 C1 = *(const float4*)(br + 20);
        float4 C2 = *(const float4*)(br + 24);
        float4 C3 = *(const float4*)(br + 28);
        float Bv[DS] = {B0.x,B0.y,B0.z,B0.w, B1.x,B1.y,B1.z,B1.w,
                        B2.x,B2.y,B2.z,B2.w, B3.x,B3.y,B3.z,B3.w};
        float Cv[DS] = {C0.x,C0.y,C0.z,C0.w, C1.x,C1.y,C1.z,C1.w,
                        C2.x,C2.y,C2.z,C2.w, C3.x,C3.y,C3.z,C3.w};
        float y = 0.f;
        #pragma unroll
        for (int s = 0; s < DS; s++) {
            float dA = __expf(dt * A2[s]);
            h[s] = dA * h[s] + dtx * Bv[s];
            y += h[s] * Cv[s];
        }
        ys[((size_t)b * LCTX + (l - LCTX)) * DI + d] = (f16)y;
    }
}

// ---------------------------------------------------------------------------
// y-combine -> fp16 A-operand for out GEMM.
// yc = 0.5 * silu(z) * (ysf + ysb + (xcf + xcb) * D)
// ---------------------------------------------------------------------------
__global__ __launch_bounds__(256) void k_ycomb(
    const f16* __restrict__ ysf, const f16* __restrict__ ysb,
    const f16* __restrict__ xcff, const f16* __restrict__ xcbf,
    const f16* __restrict__ z2f, const float* __restrict__ Dg,
    f16* __restrict__ ycf)
{
    const int t = blockIdx.x * 256 + threadIdx.x;    // 0..524287
    const int d8 = (t & 127) << 3;
    const int bo = t >> 7;
    const int o = bo & (LCTX - 1);
    const int b = bo >> 11;
    const size_t il = ((size_t)b * L_TOT + (o + LCTX)) * DI + d8;
    const size_t io = ((size_t)b * LCTX + o) * DI + d8;
    f16x8 yf  = *(const f16x8*)(ysf + io);
    f16x8 yb  = *(const f16x8*)(ysb + io);
    f16x8 cf  = *(const f16x8*)(xcff + il);
    f16x8 cbk = *(const f16x8*)(xcbf + il);
    f16x8 zv  = *(const f16x8*)(z2f + io);
    float4 d0 = *(const float4*)(Dg + d8);
    float4 d1 = *(const float4*)(Dg + d8 + 4);
    float dv[8] = {d0.x,d0.y,d0.z,d0.w, d1.x,d1.y,d1.z,d1.w};
    f16x8 r;
    #pragma unroll
    for (int c = 0; c < 8; c++) {
        float v = 0.5f * siluf((float)zv[c]) *
                  ((float)yf[c] + (float)yb[c] + ((float)cf[c] + (float)cbk[c]) * dv[c]);
        r[c] = (f16)v;
    }
    *(f16x8*)(ycf + io) = r;
}

// ---------------------------------------------------------------------------
extern "C" void kernel_launch(void* const* d_in, const int* in_sizes, int n_in,
                              void* d_out, int out_size, void* d_ws, size_t ws_size,
                              hipStream_t stream)
{
    const float* query   = (const float*)d_in[0];
    const float* context = (const float*)d_in[1];
    const float* segc    = (const float*)d_in[2];
    const float* segq    = (const float*)d_in[3];
    const float* Win     = (const float*)d_in[4];
    const float* cw      = (const float*)d_in[5];
    const float* cb      = (const float*)d_in[6];
    const float* Wx      = (const float*)d_in[7];
    const float* Wdt     = (const float*)d_in[8];
    const float* bdt     = (const float*)d_in[9];
    const float* Alog    = (const float*)d_in[10];
    const float* Dg      = (const float*)d_in[11];
    const float* Wout    = (const float*)d_in[12];
    float* out = (float*)d_out;

    char* p = (char*)d_ws;
    f16* xf    = (f16*)p;               p += (size_t)8192 * 512 * 2;       // 8 MB
    f16* winf  = (f16*)p;               p += (size_t)2048 * 512 * 2;       // 2 MB
    f16* wxf   = (f16*)p;               p += (size_t)64 * 1024 * 2;        // 128 KB
    f16* woutf = (f16*)p;               p += (size_t)512 * 1024 * 2;       // 1 MB
    f16* xif   = (f16*)p;               p += (size_t)2 * 4096 * 1024 * 2;  // 16 MB
    f16* z2f   = (f16*)p;               p += (size_t)2 * 2048 * 1024 * 2;  // 8 MB
    f16* xcff  = (f16*)p;               p += (size_t)2 * 4096 * 1024 * 2;  // 16 MB
    f16* xcbf  = (f16*)p;               p += (size_t)2 * 4096 * 1024 * 2;  // 16 MB
    float* dblf = (float*)p;            p += (size_t)2 * 4096 * 64 * 4;    // 2 MB
    float* dblb = (float*)p;            p += (size_t)2 * 4096 * 64 * 4;    // 2 MB
    f16* dtf   = (f16*)p;               p += (size_t)2 * 4096 * 1024 * 2;  // 16 MB
    f16* dtb   = (f16*)p;               p += (size_t)2 * 2048 * 1024 * 2;  // 8 MB
    float* Pg  = (float*)p;             p += (size_t)4 * 64 * 16 * 1024 * 4;  // 16 MB
    float* Og  = (float*)p;             p += (size_t)4 * 64 * 16 * 1024 * 4;  // 16 MB
    float* hsb = (float*)p;             p += (size_t)4 * 32 * 16 * 1024 * 4;  // 8 MB
    f16* ysf   = (f16*)p;               p += (size_t)2 * 2048 * 1024 * 2;  // 8 MB
    f16* ysb   = (f16*)p;               p += (size_t)2 * 2048 * 1024 * 2;  // 8 MB
    f16* ycf   = (f16*)p;               p += (size_t)2 * 2048 * 1024 * 2;  // 8 MB
    // total ~167 MB

    k_prep_x<<<dim3(2048), 256, 0, stream>>>(query, context, segc, segq, xf);
    k_prep_w<<<dim3(800), 256, 0, stream>>>(Win, Wx, Wout, winf, wxf, woutf);
    k_gx<<<dim3(64, 16), 256, 0, stream>>>(xf, winf, xif, z2f);
    k_conv<<<dim3(4096), 256, 0, stream>>>(xif, cw, cb, xcff, xcbf);
    k_gdbl<<<dim3(96), 256, 0, stream>>>(xcff, xcbf, wxf, dblf, dblb);
    k_dt<<<dim3(1024, 4, 4), 256, 0, stream>>>(dblf, dblb, Wdt, bdt, dtf, dtb);
    k_scan_p1<<<dim3(NC, 4, 4), 256, 0, stream>>>(xcff, xcbf, dblf, dblb, dtf, dtb, Alog, Pg, Og);
    k_scan_p2<<<dim3(4, 16, 4), 256, 0, stream>>>(Pg, Og, hsb);
    k_scan_p3<<<dim3(NC/2, 4, 4), 256, 0, stream>>>(xcff, xcbf, dblf, dblb, dtf, dtb, Alog, hsb, ysf, ysb);
    k_ycomb<<<dim3(2048), 256, 0, stream>>>(ysf, ysb, xcff, xcbf, z2f, Dg, ycf);
    k_gout<<<dim3(32, 8), 256, 0, stream>>>(ycf, woutf, out);
}